// Round 10
// baseline (291.418 us; speedup 1.0000x reference)
//
#include <hip/hip_runtime.h>
#include <hip/hip_cooperative_groups.h>
#include <math.h>

namespace cg = cooperative_groups;

// DCNv2 fused, f16-MFMA, single cooperative kernel (convert + grid.sync + GEMM), round 10.
// x[8,64,64,256] f32, omw[3,3,256,27], omb[27], wmat[2304,256], bias[256] -> out[8,64,64,256] f32

#define BB 8
#define HH 64
#define WW 64
#define CIN 256
#define FF 256
#define KPTS 9
#define OCH 27
#define MT 32            // pixels per block = half of one (b,oh) row
#define NS2 36           // K-steps of 64: 2304/64

typedef _Float16 half8  __attribute__((ext_vector_type(8)));
typedef _Float16 half4v __attribute__((ext_vector_type(4)));
typedef float    floatx4 __attribute__((ext_vector_type(4)));

// A-tile LDS offset (halves). Row stride 64 halves; XOR swizzle: b128 R/W <=2-way (free).
__device__ __forceinline__ int aoff(int m, int g) {
    return m * 64 + ((g ^ (m & 7)) << 3);
}

__device__ __forceinline__ half8 splat8(_Float16 v) {
    half8 r = {v, v, v, v, v, v, v, v};
    return r;
}

#define ZERO8 {(_Float16)0,(_Float16)0,(_Float16)0,(_Float16)0,(_Float16)0,(_Float16)0,(_Float16)0,(_Float16)0}

// ================= shared main body (phase1 + params + phase2) =================
__device__ __forceinline__ void dcn_body(
    const _Float16* __restrict__ xh,
    const float* __restrict__ omb,
    const _Float16* __restrict__ wsB,
    const _Float16* __restrict__ wsOM,
    const float* __restrict__ bias,
    float* __restrict__ out)
{
    __shared__ _Float16 Ah0[MT * 64];     // 4 KB each, double buffer
    __shared__ _Float16 Ah1[MT * 64];
    __shared__ float    om_s[MT][28];
    __shared__ half4v   cwS[MT][KPTS];
    __shared__ int4     caS[MT][KPTS];

    const int tid  = threadIdx.x;
    const int w    = tid >> 6;       // wave 0..3
    const int lane = tid & 63;
    const int q    = lane >> 4;
    const int lr   = lane & 15;
    const int ms   = tid >> 3;       // staged row 0..31
    const int qc   = tid & 7;        // staged 8-ch group

    const int p   = blockIdx.x;
    const int b   = p & 7;           // batch -> XCD pin
    const int r   = p >> 3;
    const int oh  = r >> 1;
    const int owb = (r & 1) * MT;
    const int pbase = (b * HH + oh) * WW + owb;

    const half8* wsOM8 = (const half8*)wsOM;
    const half8* wsB8  = (const half8*)wsB;

    // ============ Phase 1: offset/mask conv (KSTEP=64, depth-2 prefetch) ============
    const int mt1 = w & 1;
    const int nt1 = w >> 1;
    floatx4 acc1 = {0.f, 0.f, 0.f, 0.f};

    auto load1 = [&](int sp) -> half8 {
        sp = sp < NS2 - 1 ? sp : NS2 - 1;
        const int kk = sp >> 2, cb = (sp & 3) << 6;
        const int ky = kk / 3, kx = kk - ky * 3;
        const int iy = oh - 1 + ky, ix = owb + ms - 1 + kx;
        half8 v = ZERO8;
        if (iy >= 0 && iy < HH && ix >= 0 && ix < WW)
            v = *(const half8*)(xh + ((b * HH + iy) * WW + ix) * CIN + cb + qc * 8);
        return v;
    };
    auto loadB1 = [&](int sp, half8& b0, half8& b1) {
        sp = sp < NS2 - 1 ? sp : NS2 - 1;
        b0 = wsOM8[(sp * 8 + q) * 32 + nt1 * 16 + lr];
        b1 = wsOM8[(sp * 8 + 4 + q) * 32 + nt1 * 16 + lr];
    };

    half8 vpE, vpO, boE0, boE1, boO0, boO1;
    vpE = load1(0);
    vpO = load1(1);
    loadB1(0, boE0, boE1);
    loadB1(1, boO0, boO1);
    *(half8*)(Ah0 + aoff(ms, qc)) = vpE;      // step 0 data
    vpE = load1(2);

    for (int s = 0; s < NS2; s += 2) {
        __syncthreads();
        *(half8*)(Ah1 + aoff(ms, qc)) = vpO;  // step s+1 data
        vpO = load1(s + 3);
        {
            const half8 a0 = *(const half8*)(Ah0 + aoff(mt1 * 16 + lr, q));
            const half8 a1 = *(const half8*)(Ah0 + aoff(mt1 * 16 + lr, 4 + q));
            acc1 = __builtin_amdgcn_mfma_f32_16x16x32_f16(a0, boE0, acc1, 0, 0, 0);
            acc1 = __builtin_amdgcn_mfma_f32_16x16x32_f16(a1, boE1, acc1, 0, 0, 0);
        }
        loadB1(s + 2, boE0, boE1);
        __syncthreads();
        *(half8*)(Ah0 + aoff(ms, qc)) = vpE;  // step s+2 data
        vpE = load1(s + 4);
        {
            const half8 a0 = *(const half8*)(Ah1 + aoff(mt1 * 16 + lr, q));
            const half8 a1 = *(const half8*)(Ah1 + aoff(mt1 * 16 + lr, 4 + q));
            acc1 = __builtin_amdgcn_mfma_f32_16x16x32_f16(a0, boO0, acc1, 0, 0, 0);
            acc1 = __builtin_amdgcn_mfma_f32_16x16x32_f16(a1, boO1, acc1, 0, 0, 0);
        }
        loadB1(s + 3, boO0, boO1);
    }
    {
        const int och = nt1 * 16 + lr;
        if (och < OCH) {
            const float ob = omb[och];
            #pragma unroll
            for (int reg = 0; reg < 4; ++reg) {
                const int m = mt1 * 16 + q * 4 + reg;   // C/D: row=(lane>>4)*4+reg
                om_s[m][och] = acc1[reg] + ob;
            }
        }
    }
    __syncthreads();

    // ============ bilinear params ============
    for (int i = tid; i < MT * KPTS; i += 256) {
        const int m = i / KPTS, kk = i % KPTS;
        const int ky = kk / 3, kx = kk - ky * 3;
        const float dy = om_s[m][2 * kk];
        const float dx = om_s[m][2 * kk + 1];
        const float mask = 2.f / (1.f + __expf(-om_s[m][18 + kk]));
        const float py = (float)(oh - 1 + ky) + dy;
        const float px = (float)(owb + m - 1 + kx) + dx;
        const float y0f = floorf(py), x0f = floorf(px);
        const float wy1 = py - y0f, wx1 = px - x0f;
        const float wy0 = 1.f - wy1, wx0 = 1.f - wx1;
        const int y0 = (int)y0f, x0 = (int)x0f;
        const int y1 = y0 + 1, x1 = x0 + 1;
        const bool vy0 = (y0 >= 0) && (y0 < HH);
        const bool vy1 = (y1 >= 0) && (y1 < HH);
        const bool vx0 = (x0 >= 0) && (x0 < WW);
        const bool vx1 = (x1 >= 0) && (x1 < WW);
        const int y0c = min(max(y0, 0), HH - 1), y1c = min(max(y1, 0), HH - 1);
        const int x0c = min(max(x0, 0), WW - 1), x1c = min(max(x1, 0), WW - 1);
        const int rb = b * HH;
        int4 ca;
        ca.x = ((rb + y0c) * WW + x0c) * CIN;
        ca.y = ((rb + y0c) * WW + x1c) * CIN;
        ca.z = ((rb + y1c) * WW + x0c) * CIN;
        ca.w = ((rb + y1c) * WW + x1c) * CIN;
        half4v cw;
        cw.x = (_Float16)((vy0 && vx0) ? mask * wy0 * wx0 : 0.f);
        cw.y = (_Float16)((vy0 && vx1) ? mask * wy0 * wx1 : 0.f);
        cw.z = (_Float16)((vy1 && vx0) ? mask * wy1 * wx0 : 0.f);
        cw.w = (_Float16)((vy1 && vx1) ? mask * wy1 * wx1 : 0.f);
        caS[m][kk] = ca;
        cwS[m][kk] = cw;
    }
    __syncthreads();

    // ============ Phase 2: deformable GEMM (wave = 32m x 64n, depth-2 corner prefetch) ============
    floatx4 acc[2][4];
    #pragma unroll
    for (int t = 0; t < 2; ++t)
        #pragma unroll
        for (int nt = 0; nt < 4; ++nt)
            acc[t][nt] = (floatx4){0.f, 0.f, 0.f, 0.f};

    const int n0w = w * 64;

    half8  pcE0, pcE1, pcE2, pcE3, pcO0, pcO1, pcO2, pcO3;
    half4v pcwE, pcwO;

    auto pre2E = [&](int sp) {
        sp = sp < NS2 - 1 ? sp : NS2 - 1;
        const int kk = sp >> 2;
        const int co = ((sp & 3) << 6) + qc * 8;
        const int4 ca = caS[ms][kk];
        pcwE = cwS[ms][kk];
        pcE0 = *(const half8*)(xh + ca.x + co);
        pcE1 = *(const half8*)(xh + ca.y + co);
        pcE2 = *(const half8*)(xh + ca.z + co);
        pcE3 = *(const half8*)(xh + ca.w + co);
    };
    auto pre2O = [&](int sp) {
        sp = sp < NS2 - 1 ? sp : NS2 - 1;
        const int kk = sp >> 2;
        const int co = ((sp & 3) << 6) + qc * 8;
        const int4 ca = caS[ms][kk];
        pcwO = cwS[ms][kk];
        pcO0 = *(const half8*)(xh + ca.x + co);
        pcO1 = *(const half8*)(xh + ca.y + co);
        pcO2 = *(const half8*)(xh + ca.z + co);
        pcO3 = *(const half8*)(xh + ca.w + co);
    };

    half8 bP[2][4];
    auto loadB2 = [&](int sp) {
        const int kk = sp >> 2;
        const int r8 = kk * 32 + (sp & 3) * 8;
        #pragma unroll
        for (int kh = 0; kh < 2; ++kh)
            #pragma unroll
            for (int nt = 0; nt < 4; ++nt)
                bP[kh][nt] = wsB8[(size_t)(r8 + kh * 4 + q) * FF + n0w + nt * 16 + lr];
    };

    pre2E(0);
    pre2O(1);
    {
        const half8 v = pcE0 * splat8(pcwE.x) + pcE1 * splat8(pcwE.y)
                      + pcE2 * splat8(pcwE.z) + pcE3 * splat8(pcwE.w);
        *(half8*)(Ah0 + aoff(ms, qc)) = v;    // step 0 data
    }
    pre2E(2);

    for (int s = 0; s < NS2; s += 2) {
        __syncthreads();
        {
            const half8 v = pcO0 * splat8(pcwO.x) + pcO1 * splat8(pcwO.y)
                          + pcO2 * splat8(pcwO.z) + pcO3 * splat8(pcwO.w);
            *(half8*)(Ah1 + aoff(ms, qc)) = v;   // step s+1 data
        }
        pre2O(s + 3);
        loadB2(s);
        #pragma unroll
        for (int kh = 0; kh < 2; ++kh) {
            half8 afr[2];
            #pragma unroll
            for (int t = 0; t < 2; ++t)
                afr[t] = *(const half8*)(Ah0 + aoff(t * 16 + lr, kh * 4 + q));
            #pragma unroll
            for (int nt = 0; nt < 4; ++nt)
                #pragma unroll
                for (int t = 0; t < 2; ++t)
                    acc[t][nt] = __builtin_amdgcn_mfma_f32_16x16x32_f16(afr[t], bP[kh][nt], acc[t][nt], 0, 0, 0);
        }
        __syncthreads();
        {
            const half8 v = pcE0 * splat8(pcwE.x) + pcE1 * splat8(pcwE.y)
                          + pcE2 * splat8(pcwE.z) + pcE3 * splat8(pcwE.w);
            *(half8*)(Ah0 + aoff(ms, qc)) = v;   // step s+2 data
        }
        pre2E(s + 4);
        loadB2(s + 1);
        #pragma unroll
        for (int kh = 0; kh < 2; ++kh) {
            half8 afr[2];
            #pragma unroll
            for (int t = 0; t < 2; ++t)
                afr[t] = *(const half8*)(Ah1 + aoff(t * 16 + lr, kh * 4 + q));
            #pragma unroll
            for (int nt = 0; nt < 4; ++nt)
                #pragma unroll
                for (int t = 0; t < 2; ++t)
                    acc[t][nt] = __builtin_amdgcn_mfma_f32_16x16x32_f16(afr[t], bP[kh][nt], acc[t][nt], 0, 0, 0);
        }
    }

    // ============ epilogue ============
    #pragma unroll
    for (int nt = 0; nt < 4; ++nt) {
        const int f = n0w + nt * 16 + lr;
        const float bv = bias[f];
        #pragma unroll
        for (int t = 0; t < 2; ++t)
            #pragma unroll
            for (int reg = 0; reg < 4; ++reg) {
                const int m = t * 16 + q * 4 + reg;
                out[(size_t)(pbase + m) * FF + f] = acc[t][nt][reg] + bv;
            }
    }
}

// ================= cooperative all-in-one kernel =================
__global__ __launch_bounds__(256, 4) void dcn_coop(
    const float* __restrict__ x, const float* __restrict__ wmat,
    const float* __restrict__ omw,
    _Float16* __restrict__ xh, _Float16* __restrict__ wsB, _Float16* __restrict__ wsOM,
    const float* __restrict__ omb, const float* __restrict__ bias,
    float* __restrict__ out)
{
    const int p = blockIdx.x;
    // ---- convert stage: x (8192 elems/block), wmat (blocks 0..287), omw (blocks 288..575)
    #pragma unroll
    for (int j = 0; j < 4; ++j) {
        const size_t i = (((size_t)p * 4 + j) * 256 + threadIdx.x) * 8;
        const floatx4 a = *(const floatx4*)(x + i);
        const floatx4 c = *(const floatx4*)(x + i + 4);
        half8 h;
        h[0] = (_Float16)a.x; h[1] = (_Float16)a.y; h[2] = (_Float16)a.z; h[3] = (_Float16)a.w;
        h[4] = (_Float16)c.x; h[5] = (_Float16)c.y; h[6] = (_Float16)c.z; h[7] = (_Float16)c.w;
        *(half8*)(xh + i) = h;
    }
    if (p < 288) {
        const int kg = p, n = threadIdx.x;
        half8 h;
        #pragma unroll
        for (int j = 0; j < 8; ++j)
            h[j] = (_Float16)wmat[(size_t)(kg * 8 + j) * FF + n];
        ((half8*)wsB)[(size_t)kg * FF + n] = h;
    } else if (p < 576) {
        const int t = (p - 288) * 256 + threadIdx.x;
        const int k = t >> 5, n = t & 31;
        const float v = (n < OCH) ? omw[k * OCH + n] : 0.f;
        wsOM[((size_t)(k >> 3) * 32 + n) * 8 + (k & 7)] = (_Float16)v;
    }
    cg::this_grid().sync();
    // ---- main body ----
    dcn_body(xh, omb, wsB, wsOM, bias, out);
}

// ================= non-cooperative fallbacks =================
#define XBLK 4096
__global__ __launch_bounds__(256) void convert_all(
    const float* __restrict__ x, const float* __restrict__ wmat,
    const float* __restrict__ omw,
    _Float16* __restrict__ xh, _Float16* __restrict__ wsB, _Float16* __restrict__ wsOM)
{
    const int bid = blockIdx.x;
    if (bid < XBLK) {
        const size_t i = ((size_t)bid * 256 + threadIdx.x) * 8;
        const floatx4 a = *(const floatx4*)(x + i);
        const floatx4 c = *(const floatx4*)(x + i + 4);
        half8 h;
        h[0] = (_Float16)a.x; h[1] = (_Float16)a.y; h[2] = (_Float16)a.z; h[3] = (_Float16)a.w;
        h[4] = (_Float16)c.x; h[5] = (_Float16)c.y; h[6] = (_Float16)c.z; h[7] = (_Float16)c.w;
        *(half8*)(xh + i) = h;
    } else if (bid < XBLK + 288) {
        const int kg = bid - XBLK;
        const int n  = threadIdx.x;
        half8 h;
        #pragma unroll
        for (int j = 0; j < 8; ++j)
            h[j] = (_Float16)wmat[(size_t)(kg * 8 + j) * FF + n];
        ((half8*)wsB)[(size_t)kg * FF + n] = h;
    } else {
        const int t = (bid - XBLK - 288) * 256 + threadIdx.x;
        const int k = t >> 5, n = t & 31;
        const float v = (n < OCH) ? omw[k * OCH + n] : 0.f;
        wsOM[((size_t)(k >> 3) * 32 + n) * 8 + (k & 7)] = (_Float16)v;
    }
}

__global__ __launch_bounds__(256, 4) void dcn_main(
    const _Float16* __restrict__ xh, const float* __restrict__ omb,
    const _Float16* __restrict__ wsB, const _Float16* __restrict__ wsOM,
    const float* __restrict__ bias, float* __restrict__ out)
{
    dcn_body(xh, omb, wsB, wsOM, bias, out);
}

// ---------------- fp32 fallback (known-good round-1 kernel) ----------------
#define MTILE 32
#define CHUNK 64
#define NCHUNK (CIN / CHUNK)

__global__ __launch_bounds__(256) void dcn_fused(
    const float* __restrict__ x, const float* __restrict__ omw,
    const float* __restrict__ omb, const float* __restrict__ wmat,
    const float* __restrict__ bias, float* __restrict__ out)
{
    __shared__ float A[CHUNK][MTILE + 1];
    __shared__ float om_s[MTILE][28];
    __shared__ float cw[MTILE][4];
    __shared__ int   ca[MTILE][4];

    const int tid = threadIdx.x;
    const int pbase = blockIdx.x * MTILE;
    const int ccid = tid & 63;
    const int mg2 = tid >> 6;
    const int och = tid & 31;
    const int mg1 = tid >> 5;
    float acc1[4] = {0.f, 0.f, 0.f, 0.f};

    for (int kk = 0; kk < KPTS; ++kk) {
        const int ky = kk / 3, kx = kk % 3;
        for (int ch = 0; ch < NCHUNK; ++ch) {
            const int cbase = ch * CHUNK;
            __syncthreads();
            #pragma unroll
            for (int i = 0; i < 8; ++i) {
                const int m = mg2 * 8 + i;
                const int pp = pbase + m;
                const int bb = pp >> 12, oh = (pp >> 6) & 63, ow = pp & 63;
                const int iy = oh - 1 + ky, ix = ow - 1 + kx;
                float v = 0.f;
                if (iy >= 0 && iy < HH && ix >= 0 && ix < WW)
                    v = x[((bb * HH + iy) * WW + ix) * CIN + cbase + ccid];
                A[ccid][m] = v;
            }
            __syncthreads();
            if (och < OCH) {
                for (int cc = 0; cc < CHUNK; ++cc) {
                    const float bv = omw[((kk * CIN) + cbase + cc) * OCH + och];
                    #pragma unroll
                    for (int i = 0; i < 4; ++i)
                        acc1[i] += A[cc][mg1 * 4 + i] * bv;
                }
            }
        }
    }
    __syncthreads();
    if (och < OCH) {
        const float ob = omb[och];
        #pragma unroll
        for (int i = 0; i < 4; ++i)
            om_s[mg1 * 4 + i][och] = acc1[i] + ob;
    }
    __syncthreads();

    const int f4 = (tid & 63) * 4;
    const int mgc = tid >> 6;
    float acc[8][4];
    #pragma unroll
    for (int j = 0; j < 8; ++j)
        #pragma unroll
        for (int i = 0; i < 4; ++i) acc[j][i] = 0.f;

    for (int kk = 0; kk < KPTS; ++kk) {
        if (tid < MTILE) {
            const int m = tid;
            const int pp = pbase + m;
            const int bb = pp >> 12, oh = (pp >> 6) & 63, ow = pp & 63;
            const int ky = kk / 3, kx = kk % 3;
            const float dy = om_s[m][2 * kk];
            const float dx = om_s[m][2 * kk + 1];
            const float mask = 2.f / (1.f + __expf(-om_s[m][18 + kk]));
            const float py = (float)(oh - 1 + ky) + dy;
            const float px = (float)(ow - 1 + kx) + dx;
            const float y0f = floorf(py), x0f = floorf(px);
            const float wy1 = py - y0f, wx1 = px - x0f;
            const float wy0 = 1.f - wy1, wx0 = 1.f - wx1;
            const int y0 = (int)y0f, x0 = (int)x0f;
            const int y1 = y0 + 1, x1 = x0 + 1;
            const bool vy0 = (y0 >= 0) && (y0 < HH);
            const bool vy1 = (y1 >= 0) && (y1 < HH);
            const bool vx0 = (x0 >= 0) && (x0 < WW);
            const bool vx1 = (x1 >= 0) && (x1 < WW);
            const int y0c = min(max(y0, 0), HH - 1), y1c = min(max(y1, 0), HH - 1);
            const int x0c = min(max(x0, 0), WW - 1), x1c = min(max(x1, 0), WW - 1);
            const int rb = bb * HH;
            ca[m][0] = ((rb + y0c) * WW + x0c) * CIN;
            ca[m][1] = ((rb + y0c) * WW + x1c) * CIN;
            ca[m][2] = ((rb + y1c) * WW + x0c) * CIN;
            ca[m][3] = ((rb + y1c) * WW + x1c) * CIN;
            cw[m][0] = (vy0 && vx0) ? mask * wy0 * wx0 : 0.f;
            cw[m][1] = (vy0 && vx1) ? mask * wy0 * wx1 : 0.f;
            cw[m][2] = (vy1 && vx0) ? mask * wy1 * wx0 : 0.f;
            cw[m][3] = (vy1 && vx1) ? mask * wy1 * wx1 : 0.f;
        }
        for (int ch = 0; ch < NCHUNK; ++ch) {
            const int cbase = ch * CHUNK;
            __syncthreads();
            #pragma unroll
            for (int i = 0; i < 8; ++i) {
                const int m = mg2 * 8 + i;
                const int cidx = cbase + ccid;
                const float v = cw[m][0] * x[ca[m][0] + cidx]
                              + cw[m][1] * x[ca[m][1] + cidx]
                              + cw[m][2] * x[ca[m][2] + cidx]
                              + cw[m][3] * x[ca[m][3] + cidx];
                A[ccid][m] = v;
            }
            __syncthreads();
            const float* brow = wmat + (size_t)(kk * CIN + cbase) * FF + f4;
            for (int cc = 0; cc < CHUNK; ++cc) {
                const float4 bv = *(const float4*)(brow + cc * FF);
                #pragma unroll
                for (int j = 0; j < 8; ++j) {
                    const float a = A[cc][mgc * 8 + j];
                    acc[j][0] += a * bv.x;
                    acc[j][1] += a * bv.y;
                    acc[j][2] += a * bv.z;
                    acc[j][3] += a * bv.w;
                }
            }
        }
    }

    const float4 bb4 = *(const float4*)(bias + f4);
    #pragma unroll
    for (int j = 0; j < 8; ++j) {
        const int m = mgc * 8 + j;
        const int pp = pbase + m;
        float4 o;
        o.x = acc[j][0] + bb4.x;
        o.y = acc[j][1] + bb4.y;
        o.z = acc[j][2] + bb4.z;
        o.w = acc[j][3] + bb4.w;
        *(float4*)(out + (size_t)pp * FF + f4) = o;
    }
}

extern "C" void kernel_launch(void* const* d_in, const int* in_sizes, int n_in,
                              void* d_out, int out_size, void* d_ws, size_t ws_size,
                              hipStream_t stream) {
    const float* x    = (const float*)d_in[0];
    const float* omw  = (const float*)d_in[1];
    const float* omb  = (const float*)d_in[2];
    const float* wmat = (const float*)d_in[3];
    const float* bias = (const float*)d_in[4];
    float* out = (float*)d_out;

    const size_t needB  = (size_t)2304 * FF * sizeof(_Float16);    // 1,179,648 B
    const size_t needOM = (size_t)288 * 32 * 8 * sizeof(_Float16); // 147,456 B
    const size_t needX  = (size_t)BB * HH * WW * CIN * sizeof(_Float16); // 16,777,216 B

    if (ws_size >= needB + needOM + needX) {
        _Float16* wsB  = (_Float16*)d_ws;
        _Float16* wsOM = (_Float16*)((char*)d_ws + needB);
        _Float16* xh   = (_Float16*)((char*)d_ws + needB + needOM);

        void* args[9] = { (void*)&x, (void*)&wmat, (void*)&omw,
                          (void*)&xh, (void*)&wsB, (void*)&wsOM,
                          (void*)&omb, (void*)&bias, (void*)&out };
        hipError_t e = hipLaunchCooperativeKernel((const void*)dcn_coop,
                                                  dim3(BB * HH * 2), dim3(256),
                                                  args, 0, stream);
        if (e != hipSuccess) {
            // fallback: two-kernel path (round-9 structure)
            convert_all<<<XBLK + 288 + 288, 256, 0, stream>>>(x, wmat, omw, xh, wsB, wsOM);
            dcn_main<<<BB * HH * 2, 256, 0, stream>>>(xh, omb, wsB, wsOM, bias, out);
        }
    } else {
        const int nblocks = (BB * HH * WW) / MTILE;
        dcn_fused<<<nblocks, 256, 0, stream>>>(x, omw, omb, wmat, bias, out);
    }
}

// Round 11
// 160.128 us; speedup vs baseline: 1.8199x; 1.8199x over previous
//
#include <hip/hip_runtime.h>
#include <math.h>

// DCNv2 fused, f16-MFMA. Round 11 = round-7 structure (MT=64, best measured)
// + depth-2 corner prefetch in phase 2 + fatter convert blocks.
// x[8,64,64,256] f32, omw[3,3,256,27], omb[27], wmat[2304,256], bias[256] -> out[8,64,64,256] f32

#define BB 8
#define HH 64
#define WW 64
#define CIN 256
#define FF 256
#define KPTS 9
#define OCH 27
#define MT 64            // pixels per block = one (b,oh) row
#define NS2 36           // K-steps of 64: 2304/64

typedef _Float16 half8  __attribute__((ext_vector_type(8)));
typedef _Float16 half4v __attribute__((ext_vector_type(4)));
typedef float    floatx4 __attribute__((ext_vector_type(4)));

// A-tile LDS offset (halves). Row stride 64 halves (128 B); XOR swizzle of the
// 8-half k-group against (m&7): b128 reads AND writes are <=2-way (free).
__device__ __forceinline__ int aoff(int m, int g) {
    return m * 64 + ((g ^ (m & 7)) << 3);
}

__device__ __forceinline__ half8 splat8(_Float16 v) {
    half8 r = {v, v, v, v, v, v, v, v};
    return r;
}

#define ZERO8 {(_Float16)0,(_Float16)0,(_Float16)0,(_Float16)0,(_Float16)0,(_Float16)0,(_Float16)0,(_Float16)0}

// ---------------- fused pre-pass: x->f16 (1024 fat blocks), wmat/omw->f16 swizzled ----------------
#define XCBLK 1024   // x: 1024 blocks x 256 thr x 32 elems = 8,388,608
__global__ __launch_bounds__(256) void convert_all(
    const float* __restrict__ x, const float* __restrict__ wmat,
    const float* __restrict__ omw,
    _Float16* __restrict__ xh, _Float16* __restrict__ wsB, _Float16* __restrict__ wsOM)
{
    const int bid = blockIdx.x;
    if (bid < XCBLK) {
        if (xh == nullptr) return;
        #pragma unroll
        for (int j = 0; j < 4; ++j) {
            const size_t i = (((size_t)bid * 4 + j) * 256 + threadIdx.x) * 8;
            const floatx4 a = *(const floatx4*)(x + i);
            const floatx4 c = *(const floatx4*)(x + i + 4);
            half8 h;
            h[0] = (_Float16)a.x; h[1] = (_Float16)a.y; h[2] = (_Float16)a.z; h[3] = (_Float16)a.w;
            h[4] = (_Float16)c.x; h[5] = (_Float16)c.y; h[6] = (_Float16)c.z; h[7] = (_Float16)c.w;
            *(half8*)(xh + i) = h;
        }
    } else if (bid < XCBLK + 288) {
        // wsB[(k/8)*256 + n][8] = wmat[k][n]
        const int kg = bid - XCBLK;      // 0..287
        const int n  = threadIdx.x;      // 0..255
        half8 h;
        #pragma unroll
        for (int j = 0; j < 8; ++j)
            h[j] = (_Float16)wmat[(size_t)(kg * 8 + j) * FF + n];
        ((half8*)wsB)[(size_t)kg * FF + n] = h;
    } else {
        // wsOM[(k/8)*32 + n][8] = omw[k][n] (n>=27 -> 0)
        const int t = (bid - XCBLK - 288) * 256 + threadIdx.x;  // 288*256 = 2304*32
        const int k = t >> 5, n = t & 31;
        const float v = (n < OCH) ? omw[k * OCH + n] : 0.f;
        wsOM[((size_t)(k >> 3) * 32 + n) * 8 + (k & 7)] = (_Float16)v;
    }
}

// ---------------- main fused kernel ----------------
template <bool F16X>
__global__ __launch_bounds__(512, 4) void dcn_mfma6(
    const float* __restrict__ x,
    const _Float16* __restrict__ xh,
    const float* __restrict__ omb,
    const _Float16* __restrict__ wsB,
    const _Float16* __restrict__ wsOM,
    const float* __restrict__ bias,
    float* __restrict__ out)
{
    __shared__ _Float16 Ah0[MT * 64];     // 8 KB each, double buffer
    __shared__ _Float16 Ah1[MT * 64];
    __shared__ float    om_s[MT][28];     // 7 KB
    __shared__ half4v   cwS[MT][KPTS];    // 4.5 KB
    __shared__ int4     caS[MT][KPTS];    // 9 KB

    const int tid  = threadIdx.x;
    const int w    = tid >> 6;       // wave 0..7
    const int lane = tid & 63;
    const int q    = lane >> 4;      // k-quad 0..3
    const int lr   = lane & 15;
    const int ms   = tid >> 3;       // staged row 0..63
    const int qc   = tid & 7;        // staged 8-ch group 0..7

    // batch -> XCD pinning (b = blockIdx%8); block = one (b,oh) row
    const int p  = blockIdx.x;
    const int b  = p & 7;
    const int oh = p >> 3;
    const int pbase = (b * HH + oh) * WW;

    const half8* wsOM8 = (const half8*)wsOM;
    const half8* wsB8  = (const half8*)wsB;

    // ============ Phase 1: offset/mask conv via MFMA (KSTEP=64, 4m x 2n waves) ============
    const int mt1 = w & 3;
    const int nt1 = w >> 2;
    floatx4 acc1 = {0.f, 0.f, 0.f, 0.f};

    auto load1 = [&](int sp) -> half8 {
        sp = sp < NS2 - 1 ? sp : NS2 - 1;
        const int kk = sp >> 2, cb = (sp & 3) << 6;
        const int ky = kk / 3, kx = kk - ky * 3;
        const int iy = oh - 1 + ky, ix = ms - 1 + kx;
        half8 v = ZERO8;
        if (iy >= 0 && iy < HH && ix >= 0 && ix < WW) {
            const int idx = ((b * HH + iy) * WW + ix) * CIN + cb + qc * 8;
            if constexpr (F16X) {
                v = *(const half8*)(xh + idx);
            } else {
                const floatx4 lo = *(const floatx4*)(x + idx);
                const floatx4 hi = *(const floatx4*)(x + idx + 4);
                v[0] = (_Float16)lo.x; v[1] = (_Float16)lo.y;
                v[2] = (_Float16)lo.z; v[3] = (_Float16)lo.w;
                v[4] = (_Float16)hi.x; v[5] = (_Float16)hi.y;
                v[6] = (_Float16)hi.z; v[7] = (_Float16)hi.w;
            }
        }
        return v;
    };
    auto loadB1 = [&](int sp, half8& b0, half8& b1) {
        sp = sp < NS2 - 1 ? sp : NS2 - 1;
        b0 = wsOM8[(sp * 8 + q) * 32 + nt1 * 16 + lr];
        b1 = wsOM8[(sp * 8 + 4 + q) * 32 + nt1 * 16 + lr];
    };

    half8 vp;
    half8 bo00, bo01, bo10, bo11;
    {
        const half8 v0 = load1(0);
        *(half8*)(Ah0 + aoff(ms, qc)) = v0;
        vp = load1(1);
        loadB1(0, bo00, bo01);
    }
    for (int s = 0; s < NS2; s += 2) {
        __syncthreads();
        *(half8*)(Ah1 + aoff(ms, qc)) = vp;       // data for step s+1
        vp = load1(s + 2);
        loadB1(s + 1, bo10, bo11);
        {
            const half8 a0 = *(const half8*)(Ah0 + aoff(mt1 * 16 + lr, q));
            const half8 a1 = *(const half8*)(Ah0 + aoff(mt1 * 16 + lr, 4 + q));
            acc1 = __builtin_amdgcn_mfma_f32_16x16x32_f16(a0, bo00, acc1, 0, 0, 0);
            acc1 = __builtin_amdgcn_mfma_f32_16x16x32_f16(a1, bo01, acc1, 0, 0, 0);
        }
        __syncthreads();
        *(half8*)(Ah0 + aoff(ms, qc)) = vp;       // data for step s+2
        vp = load1(s + 3);
        loadB1(s + 2, bo00, bo01);
        {
            const half8 a0 = *(const half8*)(Ah1 + aoff(mt1 * 16 + lr, q));
            const half8 a1 = *(const half8*)(Ah1 + aoff(mt1 * 16 + lr, 4 + q));
            acc1 = __builtin_amdgcn_mfma_f32_16x16x32_f16(a0, bo10, acc1, 0, 0, 0);
            acc1 = __builtin_amdgcn_mfma_f32_16x16x32_f16(a1, bo11, acc1, 0, 0, 0);
        }
    }
    {
        const int och = nt1 * 16 + lr;
        if (och < OCH) {
            const float ob = omb[och];
            #pragma unroll
            for (int reg = 0; reg < 4; ++reg) {
                const int m = mt1 * 16 + q * 4 + reg;   // C/D: row=(lane>>4)*4+reg
                om_s[m][och] = acc1[reg] + ob;
            }
        }
    }
    __syncthreads();

    // ============ bilinear params ============
    for (int i = tid; i < MT * KPTS; i += 512) {
        const int m = i / KPTS, kk = i % KPTS;
        const int ky = kk / 3, kx = kk - ky * 3;
        const float dy = om_s[m][2 * kk];
        const float dx = om_s[m][2 * kk + 1];
        const float mask = 2.f / (1.f + __expf(-om_s[m][18 + kk]));
        const float py = (float)(oh - 1 + ky) + dy;
        const float px = (float)(m - 1 + kx) + dx;
        const float y0f = floorf(py), x0f = floorf(px);
        const float wy1 = py - y0f, wx1 = px - x0f;
        const float wy0 = 1.f - wy1, wx0 = 1.f - wx1;
        const int y0 = (int)y0f, x0 = (int)x0f;
        const int y1 = y0 + 1, x1 = x0 + 1;
        const bool vy0 = (y0 >= 0) && (y0 < HH);
        const bool vy1 = (y1 >= 0) && (y1 < HH);
        const bool vx0 = (x0 >= 0) && (x0 < WW);
        const bool vx1 = (x1 >= 0) && (x1 < WW);
        const int y0c = min(max(y0, 0), HH - 1), y1c = min(max(y1, 0), HH - 1);
        const int x0c = min(max(x0, 0), WW - 1), x1c = min(max(x1, 0), WW - 1);
        const int rb = b * HH;
        int4 ca;
        ca.x = ((rb + y0c) * WW + x0c) * CIN;
        ca.y = ((rb + y0c) * WW + x1c) * CIN;
        ca.z = ((rb + y1c) * WW + x0c) * CIN;
        ca.w = ((rb + y1c) * WW + x1c) * CIN;
        half4v cw;
        cw.x = (_Float16)((vy0 && vx0) ? mask * wy0 * wx0 : 0.f);
        cw.y = (_Float16)((vy0 && vx1) ? mask * wy0 * wx1 : 0.f);
        cw.z = (_Float16)((vy1 && vx0) ? mask * wy1 * wx0 : 0.f);
        cw.w = (_Float16)((vy1 && vx1) ? mask * wy1 * wx1 : 0.f);
        caS[m][kk] = ca;
        cwS[m][kk] = cw;
    }
    __syncthreads();

    // ============ Phase 2: deformable GEMM (wave = 64m x 32n; depth-2 corner prefetch) ============
    floatx4 acc[4][2];
    #pragma unroll
    for (int mt = 0; mt < 4; ++mt)
        #pragma unroll
        for (int nt = 0; nt < 2; ++nt)
            acc[mt][nt] = (floatx4){0.f, 0.f, 0.f, 0.f};

    const int n0w = w * 32;   // wave's 32-wide n-slice: wsB read once per block

    half8  pcE0, pcE1, pcE2, pcE3;   // even-step pending corners
    half8  pcO0, pcO1, pcO2, pcO3;   // odd-step pending corners
    half4v pcwE, pcwO;
    floatx4 fa0, fb0, fa1, fb1, fa2, fb2, fa3, fb3;  // f32 fallback corners (reused E/O alternately)

    auto pre2E = [&](int sp) {
        sp = sp < NS2 - 1 ? sp : NS2 - 1;
        const int kk = sp >> 2;
        const int co = ((sp & 3) << 6) + qc * 8;
        const int4 ca = caS[ms][kk];
        pcwE = cwS[ms][kk];
        if constexpr (F16X) {
            pcE0 = *(const half8*)(xh + ca.x + co);
            pcE1 = *(const half8*)(xh + ca.y + co);
            pcE2 = *(const half8*)(xh + ca.z + co);
            pcE3 = *(const half8*)(xh + ca.w + co);
        } else {
            fa0 = *(const floatx4*)(x + ca.x + co); fb0 = *(const floatx4*)(x + ca.x + co + 4);
            fa1 = *(const floatx4*)(x + ca.y + co); fb1 = *(const floatx4*)(x + ca.y + co + 4);
            fa2 = *(const floatx4*)(x + ca.z + co); fb2 = *(const floatx4*)(x + ca.z + co + 4);
            fa3 = *(const floatx4*)(x + ca.w + co); fb3 = *(const floatx4*)(x + ca.w + co + 4);
        }
    };
    auto pre2O = [&](int sp) {
        sp = sp < NS2 - 1 ? sp : NS2 - 1;
        const int kk = sp >> 2;
        const int co = ((sp & 3) << 6) + qc * 8;
        const int4 ca = caS[ms][kk];
        pcwO = cwS[ms][kk];
        if constexpr (F16X) {
            pcO0 = *(const half8*)(xh + ca.x + co);
            pcO1 = *(const half8*)(xh + ca.y + co);
            pcO2 = *(const half8*)(xh + ca.z + co);
            pcO3 = *(const half8*)(xh + ca.w + co);
        } else {
            fa0 = *(const floatx4*)(x + ca.x + co); fb0 = *(const floatx4*)(x + ca.x + co + 4);
            fa1 = *(const floatx4*)(x + ca.y + co); fb1 = *(const floatx4*)(x + ca.y + co + 4);
            fa2 = *(const floatx4*)(x + ca.z + co); fb2 = *(const floatx4*)(x + ca.z + co + 4);
            fa3 = *(const floatx4*)(x + ca.w + co); fb3 = *(const floatx4*)(x + ca.w + co + 4);
        }
    };
    auto combE = [&]() -> half8 {
        if constexpr (F16X) {
            return pcE0 * splat8(pcwE.x) + pcE1 * splat8(pcwE.y)
                 + pcE2 * splat8(pcwE.z) + pcE3 * splat8(pcwE.w);
        } else {
            const float w0 = (float)pcwE.x, w1 = (float)pcwE.y;
            const float w2 = (float)pcwE.z, w3 = (float)pcwE.w;
            const floatx4 lo = w0 * fa0 + w1 * fa1 + w2 * fa2 + w3 * fa3;
            const floatx4 hi = w0 * fb0 + w1 * fb1 + w2 * fb2 + w3 * fb3;
            half8 r;
            r[0] = (_Float16)lo.x; r[1] = (_Float16)lo.y;
            r[2] = (_Float16)lo.z; r[3] = (_Float16)lo.w;
            r[4] = (_Float16)hi.x; r[5] = (_Float16)hi.y;
            r[6] = (_Float16)hi.z; r[7] = (_Float16)hi.w;
            return r;
        }
    };
    auto combO = [&]() -> half8 {
        if constexpr (F16X) {
            return pcO0 * splat8(pcwO.x) + pcO1 * splat8(pcwO.y)
                 + pcO2 * splat8(pcwO.z) + pcO3 * splat8(pcwO.w);
        } else {
            const float w0 = (float)pcwO.x, w1 = (float)pcwO.y;
            const float w2 = (float)pcwO.z, w3 = (float)pcwO.w;
            const floatx4 lo = w0 * fa0 + w1 * fa1 + w2 * fa2 + w3 * fa3;
            const floatx4 hi = w0 * fb0 + w1 * fb1 + w2 * fb2 + w3 * fb3;
            half8 r;
            r[0] = (_Float16)lo.x; r[1] = (_Float16)lo.y;
            r[2] = (_Float16)lo.z; r[3] = (_Float16)lo.w;
            r[4] = (_Float16)hi.x; r[5] = (_Float16)hi.y;
            r[6] = (_Float16)hi.z; r[7] = (_Float16)hi.w;
            return r;
        }
    };

    half8 bPa[2][2], bPb[2][2];   // [k-half][n-tile], double-buffered
    auto loadB2 = [&](int sp, half8 (&bP)[2][2]) {
        sp = sp < NS2 - 1 ? sp : NS2 - 1;
        const int r8 = (sp >> 2) * 32 + (sp & 3) * 8;
        #pragma unroll
        for (int kh = 0; kh < 2; ++kh)
            #pragma unroll
            for (int nt = 0; nt < 2; ++nt)
                bP[kh][nt] = wsB8[(size_t)(r8 + kh * 4 + q) * FF + n0w + nt * 16 + lr];
    };

    // prologue: corners for steps 0,1 in flight; step-0 staged; corners step 2 issued; B step 0.
    pre2E(0);
    pre2O(1);
    {
        const half8 v = combE();
        *(half8*)(Ah0 + aoff(ms, qc)) = v;     // step 0 data
    }
    pre2E(2);
    loadB2(0, bPa);

    for (int s = 0; s < NS2; s += 2) {
        __syncthreads();
        {
            const half8 v = combO();           // step s+1 data
            *(half8*)(Ah1 + aoff(ms, qc)) = v;
        }
        pre2O(s + 3);
        loadB2(s + 1, bPb);
        #pragma unroll
        for (int kh = 0; kh < 2; ++kh) {
            half8 afr[4];
            #pragma unroll
            for (int mt = 0; mt < 4; ++mt)
                afr[mt] = *(const half8*)(Ah0 + aoff(mt * 16 + lr, kh * 4 + q));
            #pragma unroll
            for (int nt = 0; nt < 2; ++nt)
                #pragma unroll
                for (int mt = 0; mt < 4; ++mt)
                    acc[mt][nt] = __builtin_amdgcn_mfma_f32_16x16x32_f16(afr[mt], bPa[kh][nt], acc[mt][nt], 0, 0, 0);
        }
        __syncthreads();
        {
            const half8 v = combE();           // step s+2 data
            *(half8*)(Ah0 + aoff(ms, qc)) = v;
        }
        pre2E(s + 4);
        loadB2(s + 2, bPa);
        #pragma unroll
        for (int kh = 0; kh < 2; ++kh) {
            half8 afr[4];
            #pragma unroll
            for (int mt = 0; mt < 4; ++mt)
                afr[mt] = *(const half8*)(Ah1 + aoff(mt * 16 + lr, kh * 4 + q));
            #pragma unroll
            for (int nt = 0; nt < 2; ++nt)
                #pragma unroll
                for (int mt = 0; mt < 4; ++mt)
                    acc[mt][nt] = __builtin_amdgcn_mfma_f32_16x16x32_f16(afr[mt], bPb[kh][nt], acc[mt][nt], 0, 0, 0);
        }
    }

    // ============ epilogue ============
    #pragma unroll
    for (int nt = 0; nt < 2; ++nt) {
        const int f = n0w + nt * 16 + lr;
        const float bv = bias[f];
        #pragma unroll
        for (int mt = 0; mt < 4; ++mt)
            #pragma unroll
            for (int reg = 0; reg < 4; ++reg) {
                const int m = mt * 16 + q * 4 + reg;
                out[(size_t)(pbase + m) * FF + f] = acc[mt][nt][reg] + bv;
            }
    }
}

// ---------------- fp32 fallback (known-good round-1 kernel) ----------------
#define MTILE 32
#define CHUNK 64
#define NCHUNK (CIN / CHUNK)

__global__ __launch_bounds__(256) void dcn_fused(
    const float* __restrict__ x, const float* __restrict__ omw,
    const float* __restrict__ omb, const float* __restrict__ wmat,
    const float* __restrict__ bias, float* __restrict__ out)
{
    __shared__ float A[CHUNK][MTILE + 1];
    __shared__ float om_s[MTILE][28];
    __shared__ float cw[MTILE][4];
    __shared__ int   ca[MTILE][4];

    const int tid = threadIdx.x;
    const int pbase = blockIdx.x * MTILE;
    const int ccid = tid & 63;
    const int mg2 = tid >> 6;
    const int och = tid & 31;
    const int mg1 = tid >> 5;
    float acc1[4] = {0.f, 0.f, 0.f, 0.f};

    for (int kk = 0; kk < KPTS; ++kk) {
        const int ky = kk / 3, kx = kk % 3;
        for (int ch = 0; ch < NCHUNK; ++ch) {
            const int cbase = ch * CHUNK;
            __syncthreads();
            #pragma unroll
            for (int i = 0; i < 8; ++i) {
                const int m = mg2 * 8 + i;
                const int pp = pbase + m;
                const int bb = pp >> 12, oh = (pp >> 6) & 63, ow = pp & 63;
                const int iy = oh - 1 + ky, ix = ow - 1 + kx;
                float v = 0.f;
                if (iy >= 0 && iy < HH && ix >= 0 && ix < WW)
                    v = x[((bb * HH + iy) * WW + ix) * CIN + cbase + ccid];
                A[ccid][m] = v;
            }
            __syncthreads();
            if (och < OCH) {
                for (int cc = 0; cc < CHUNK; ++cc) {
                    const float bv = omw[((kk * CIN) + cbase + cc) * OCH + och];
                    #pragma unroll
                    for (int i = 0; i < 4; ++i)
                        acc1[i] += A[cc][mg1 * 4 + i] * bv;
                }
            }
        }
    }
    __syncthreads();
    if (och < OCH) {
        const float ob = omb[och];
        #pragma unroll
        for (int i = 0; i < 4; ++i)
            om_s[mg1 * 4 + i][och] = acc1[i] + ob;
    }
    __syncthreads();

    const int f4 = (tid & 63) * 4;
    const int mgc = tid >> 6;
    float acc[8][4];
    #pragma unroll
    for (int j = 0; j < 8; ++j)
        #pragma unroll
        for (int i = 0; i < 4; ++i) acc[j][i] = 0.f;

    for (int kk = 0; kk < KPTS; ++kk) {
        if (tid < MTILE) {
            const int m = tid;
            const int pp = pbase + m;
            const int bb = pp >> 12, oh = (pp >> 6) & 63, ow = pp & 63;
            const int ky = kk / 3, kx = kk % 3;
            const float dy = om_s[m][2 * kk];
            const float dx = om_s[m][2 * kk + 1];
            const float mask = 2.f / (1.f + __expf(-om_s[m][18 + kk]));
            const float py = (float)(oh - 1 + ky) + dy;
            const float px = (float)(ow - 1 + kx) + dx;
            const float y0f = floorf(py), x0f = floorf(px);
            const float wy1 = py - y0f, wx1 = px - x0f;
            const float wy0 = 1.f - wy1, wx0 = 1.f - wx1;
            const int y0 = (int)y0f, x0 = (int)x0f;
            const int y1 = y0 + 1, x1 = x0 + 1;
            const bool vy0 = (y0 >= 0) && (y0 < HH);
            const bool vy1 = (y1 >= 0) && (y1 < HH);
            const bool vx0 = (x0 >= 0) && (x0 < WW);
            const bool vx1 = (x1 >= 0) && (x1 < WW);
            const int y0c = min(max(y0, 0), HH - 1), y1c = min(max(y1, 0), HH - 1);
            const int x0c = min(max(x0, 0), WW - 1), x1c = min(max(x1, 0), WW - 1);
            const int rb = bb * HH;
            ca[m][0] = ((rb + y0c) * WW + x0c) * CIN;
            ca[m][1] = ((rb + y0c) * WW + x1c) * CIN;
            ca[m][2] = ((rb + y1c) * WW + x0c) * CIN;
            ca[m][3] = ((rb + y1c) * WW + x1c) * CIN;
            cw[m][0] = (vy0 && vx0) ? mask * wy0 * wx0 : 0.f;
            cw[m][1] = (vy0 && vx1) ? mask * wy0 * wx1 : 0.f;
            cw[m][2] = (vy1 && vx0) ? mask * wy1 * wx0 : 0.f;
            cw[m][3] = (vy1 && vx1) ? mask * wy1 * wx1 : 0.f;
        }
        for (int ch = 0; ch < NCHUNK; ++ch) {
            const int cbase = ch * CHUNK;
            __syncthreads();
            #pragma unroll
            for (int i = 0; i < 8; ++i) {
                const int m = mg2 * 8 + i;
                const int cidx = cbase + ccid;
                const float v = cw[m][0] * x[ca[m][0] + cidx]
                              + cw[m][1] * x[ca[m][1] + cidx]
                              + cw[m][2] * x[ca[m][2] + cidx]
                              + cw[m][3] * x[ca[m][3] + cidx];
                A[ccid][m] = v;
            }
            __syncthreads();
            const float* brow = wmat + (size_t)(kk * CIN + cbase) * FF + f4;
            for (int cc = 0; cc < CHUNK; ++cc) {
                const float4 bv = *(const float4*)(brow + cc * FF);
                #pragma unroll
                for (int j = 0; j < 8; ++j) {
                    const float a = A[cc][mgc * 8 + j];
                    acc[j][0] += a * bv.x;
                    acc[j][1] += a * bv.y;
                    acc[j][2] += a * bv.z;
                    acc[j][3] += a * bv.w;
                }
            }
        }
    }

    const float4 bb4 = *(const float4*)(bias + f4);
    #pragma unroll
    for (int j = 0; j < 8; ++j) {
        const int m = mgc * 8 + j;
        const int pp = pbase + m;
        float4 o;
        o.x = acc[j][0] + bb4.x;
        o.y = acc[j][1] + bb4.y;
        o.z = acc[j][2] + bb4.z;
        o.w = acc[j][3] + bb4.w;
        *(float4*)(out + (size_t)pp * FF + f4) = o;
    }
}

extern "C" void kernel_launch(void* const* d_in, const int* in_sizes, int n_in,
                              void* d_out, int out_size, void* d_ws, size_t ws_size,
                              hipStream_t stream) {
    const float* x    = (const float*)d_in[0];
    const float* omw  = (const float*)d_in[1];
    const float* omb  = (const float*)d_in[2];
    const float* wmat = (const float*)d_in[3];
    const float* bias = (const float*)d_in[4];
    float* out = (float*)d_out;

    const size_t needB  = (size_t)2304 * FF * sizeof(_Float16);    // 1,179,648 B
    const size_t needOM = (size_t)288 * 32 * 8 * sizeof(_Float16); // 147,456 B
    const size_t needX  = (size_t)BB * HH * WW * CIN * sizeof(_Float16); // 16,777,216 B

    if (ws_size >= needB + needOM + needX) {
        _Float16* wsB  = (_Float16*)d_ws;
        _Float16* wsOM = (_Float16*)((char*)d_ws + needB);
        _Float16* xh   = (_Float16*)((char*)d_ws + needB + needOM);
        convert_all<<<XCBLK + 288 + 288, 256, 0, stream>>>(x, wmat, omw, xh, wsB, wsOM);
        dcn_mfma6<true><<<BB * HH, 512, 0, stream>>>(x, xh, omb, wsB, wsOM, bias, out);
    } else if (ws_size >= needB + needOM) {
        _Float16* wsB  = (_Float16*)d_ws;
        _Float16* wsOM = (_Float16*)((char*)d_ws + needB);
        convert_all<<<XCBLK + 288 + 288, 256, 0, stream>>>(x, wmat, omw, nullptr, wsB, wsOM);
        dcn_mfma6<false><<<BB * HH, 512, 0, stream>>>(x, nullptr, omb, wsB, wsOM, bias, out);
    } else {
        const int nblocks = (BB * HH * WW) / MTILE;
        dcn_fused<<<nblocks, 256, 0, stream>>>(x, omw, omb, wmat, bias, out);
    }
}